// Round 19
// baseline (49.369 us; speedup 1.0000x reference)
//
#include <hip/hip_runtime.h>
#include <hip/hip_fp16.h>
#include <math.h>

#define N_COL 512
#define ALPHA 0.1f
#define CHUNK 16
#define HALO 12
#define OSTRIDE_H 18                     // 16 marker slots + dummy 16 (+pad); even
#define ISTRIDE_H 548                    // halves; even (half2-aligned rows)

// input LDS addressing (halves): col c -> c + 2*(c>>5).
__device__ __forceinline__ int idx_h(int c) { return c + ((c >> 5) << 1); }

// ---------------------------------------------------------------------------
// Fused windowed-Condat TV prox + sparsemax (r17 kernel, re-packaged).
// Round 19: 4 waves per block (256 threads, 8 rows/block). Total work is
// 8192 waves; 4-wave WGs give 8 blocks/CU (LDS-capped exactly) = 32 waves/CU
// -- the HW ceiling, 2x the ~16-wave plateau seen with 1-wave WGs (r15/r17)
// and the zero-surplus starvation of r18. Machine: exact reference Condat on
// +/-12-halo windows (L <= 40) over fp16-LDS input, deferred-flush 2-read
// body, marker output (1 LDS write + mask bit per flush), exact early-exit;
// register forward-fill fused with marker load; dual-row half-wave Newton
// sparsemax; direct 4x float4 store per lane.
// ---------------------------------------------------------------------------
__global__ __launch_bounds__(256) void fused_kernel(const float* __restrict__ x,
                                                    float* __restrict__ z) {
  __shared__ __half sin_[8 * ISTRIDE_H];    // 8.8 KB staged input rows (fp16)
  __shared__ __half sout[256 * OSTRIDE_H];  // 9.2 KB marker slots (lane-private)
  const int n = N_COL;
  const float lam = ALPHA;
  const int t = threadIdx.x;
  const int wave = t >> 6;
  const int lane = t & 63;
  const int rowInBlock = (wave << 1) | (lane >> 5);   // 0..7
  int cid = lane & 31;                   // 32 chunks per row
  int oc0 = cid << 4;                    // output cols [oc0, oc0+16)
  int oc1 = oc0 + CHUNK;
  int lo = max(0, oc0 - HALO);
  int hi = min(n, oc1 + HALO);
  int L = hi - lo;                       // 28..40
  __half* sor = sout + t * OSTRIDE_H;    // lane-private marker buffer

  // ---- Phase 0: stage 8 rows into LDS as fp16 (coalesced float4 reads) ----
  {
    const float4* gx4 = (const float4*)(x + (size_t)(blockIdx.x * 8) * n);
#pragma unroll
    for (int j = 0; j < 4; ++j) {
      int flat4 = (j << 8) | t;          // [0, 1024)
      float4 v = gx4[flat4];
      int r = flat4 >> 7;                // 128 float4 per row
      int c = (flat4 & 127) << 2;        // c%4==0 -> idx_h even
      int b = r * ISTRIDE_H + idx_h(c);  // even
      __half2* p = (__half2*)(sin_ + b);
      p[0] = __floats2half2_rn(v.x, v.y);
      p[1] = __floats2half2_rn(v.z, v.w);
    }
    if (t < 8) {
      float wl = x[((size_t)(blockIdx.x * 8) + t) * n + (n - 1)];
      __half hwl = __float2half(wl);
      int b = t * ISTRIDE_H;
      sin_[b + 544] = hwl;               // idx_h(512)
      sin_[b + 545] = hwl;               // idx_h(513)
      sin_[b + 546] = hwl;               // idx_h(514)
    }
  }
  __syncthreads();

  const __half* swin = sin_ + rowInBlock * ISTRIDE_H;
#define RD(j) __half2float(swin[idx_h(lo + (j))])

  // ---- Phase 1: windowed Condat machine (2-read deferred-flush, markers) ----
  int k = 0, k0 = 0, km = 0, kp = 0;
  float w0 = RD(0);
  float vmin = w0 - lam, vmax = w0 + lam, umin = lam, umax = -lam;
  bool done = false, Dp = false, Ep = false;
  unsigned mask = 0u;
  int budget = 12 * L;

  while (budget > 0 && __ballot(!done) != 0ull) {
    // ---- loop1: scan cases D/E/F ----
    while (budget > 0) {
      if (__ballot((k < L - 1) & !done) == 0ull) break;
      budget -= 4;
#pragma unroll
      for (int u = 0; u < 4; ++u) {
        float a = RD(k);                 // = w[k0n] when a flush is pending
        float b = RD(k + 1);
        // deferred flush fix-up (no-op when Dp=Ep=false)
        vmin = Dp ? a : (Ep ? a - 2.f * lam : vmin);
        vmax = Dp ? a + 2.f * lam : (Ep ? a : vmax);

        bool act = (k < L - 1) & !done;
        float umin1 = umin + b - vmin;
        float umax1 = umax + b - vmax;
        bool D = act & (umin1 < -lam);
        bool E = act & !D & (umax1 > lam);
        bool F = act & !D & !E;
        bool flush = D | E;

        int k0n = D ? km + 1 : kp + 1;   // act lanes: <= L-1
        float fv = D ? vmin : vmax;
        // marker write: segment [k0, k0n) overlaps chunk iff lo+k0n > oc0
        bool ovl = flush & (lo + k0n > oc0);
        int slot = max(lo + k0 - oc0, 0);
        sor[ovl ? slot : 16] = __float2half(fv);
        mask |= ovl ? (1u << slot) : 0u;
        done = done | (flush & (lo + k0n >= oc1));

        int kF = k + 1;
        bool g1 = F & (umin1 >= lam);
        bool g2 = F & (umax1 <= -lam);
        float rden = __builtin_amdgcn_rcpf((float)(kF - k0 + 1));

        k  = F ? kF : (flush ? k0n : k);
        k0 = flush ? k0n : k0;
        km = flush ? k0n : (g1 ? kF : km);
        kp = flush ? k0n : (g2 ? kF : kp);
        vmin = g1 ? vmin + (umin1 - lam) * rden : vmin;   // D/E deferred
        vmax = g2 ? vmax + (umax1 + lam) * rden : vmax;
        umin = (flush | g1) ? lam  : (F ? umin1 : umin);
        umax = (flush | g2) ? -lam : (F ? umax1 : umax);
        Dp = D; Ep = E;
      }
    }

    {  // ---- loop2: one terminal step (A/B/C) ----
      bool act = (k >= L - 1) & !done;
      // fix-up pending flush for lanes that hit the boundary right after D/E
      float a2 = RD(k);                  // k <= L -> col <= 512 (padded)
      bool fD = act & Dp, fE = act & Ep;
      vmin = fD ? a2 : (fE ? a2 - 2.f * lam : vmin);
      vmax = fD ? a2 + 2.f * lam : (fE ? a2 : vmax);
      Dp = Dp & !act; Ep = Ep & !act;

      bool A  = act & (umin < 0.f);
      bool Bb = act & !A & (umax > 0.f);
      bool C  = act & !A & !Bb;
      int k0n = min(A ? km + 1 : kp + 1, L);
      float wk0 = RD(min(k0n, L - 1));               // reference clip
      float fv = A ? vmin : (Bb ? vmax :
                 vmin + umin * __builtin_amdgcn_rcpf((float)(k - k0 + 1)));
      int gend = C ? hi : (lo + k0n);                // segment end (global)
      bool wseg = A | Bb | C;
      bool ovl = wseg & (gend > oc0);
      int slot = max(lo + k0 - oc0, 0);
      sor[ovl ? slot : 16] = __float2half(fv);
      mask |= ovl ? (1u << slot) : 0u;
      done = done | (wseg & (gend >= oc1));

      float umax_n = Bb ? -lam : (A ? wk0 + lam - vmax : umax);  // old vmax
      float umin_n = A ? lam  : (Bb ? wk0 - lam - vmin : umin);  // old vmin
      vmin = A ? wk0 : vmin;
      vmax = Bb ? wk0 : vmax;
      umin = umin_n; umax = umax_n;
      k  = (A | Bb) ? k0n : k;
      k0 = (A | Bb) ? k0n : k0;
      km = A ? k0n : km;
      kp = Bb ? k0n : kp;
      budget -= 1;
    }
  }
  // no barrier: sout is lane-private from here on

  // ---- Phase 2: register forward-fill + dual-row sparsemax + direct store ----
  {
    float f0,f1,f2,f3,f4,f5,f6,f7,f8,f9,fa,fb,fc,fd,fe,ff;
    {
      const __half2* p = (const __half2*)sor;
      __half2 h;
      h = p[0]; f0 = __low2float(h); f1 = __high2float(h);
      h = p[1]; f2 = __low2float(h); f3 = __high2float(h);
      h = p[2]; f4 = __low2float(h); f5 = __high2float(h);
      h = p[3]; f6 = __low2float(h); f7 = __high2float(h);
      h = p[4]; f8 = __low2float(h); f9 = __high2float(h);
      h = p[5]; fa = __low2float(h); fb = __high2float(h);
      h = p[6]; fc = __low2float(h); fd = __high2float(h);
      h = p[7]; fe = __low2float(h); ff = __high2float(h);
    }
    // forward fill from marker mask (bit 0 guaranteed when machine completed)
    float cur = (mask & 1u) ? f0 : 0.f;
    float v0 = cur;
    cur = (mask & (1u<<1))  ? f1 : cur; float v1 = cur;
    cur = (mask & (1u<<2))  ? f2 : cur; float v2 = cur;
    cur = (mask & (1u<<3))  ? f3 : cur; float v3 = cur;
    cur = (mask & (1u<<4))  ? f4 : cur; float v4 = cur;
    cur = (mask & (1u<<5))  ? f5 : cur; float v5 = cur;
    cur = (mask & (1u<<6))  ? f6 : cur; float v6 = cur;
    cur = (mask & (1u<<7))  ? f7 : cur; float v7 = cur;
    cur = (mask & (1u<<8))  ? f8 : cur; float v8 = cur;
    cur = (mask & (1u<<9))  ? f9 : cur; float v9 = cur;
    cur = (mask & (1u<<10)) ? fa : cur; float va = cur;
    cur = (mask & (1u<<11)) ? fb : cur; float vb = cur;
    cur = (mask & (1u<<12)) ? fc : cur; float vc = cur;
    cur = (mask & (1u<<13)) ? fd : cur; float vd = cur;
    cur = (mask & (1u<<14)) ? fe : cur; float ve = cur;
    cur = (mask & (1u<<15)) ? ff : cur; float vf = cur;

    float m = fmaxf(fmaxf(fmaxf(fmaxf(v0,v1),fmaxf(v2,v3)),
                          fmaxf(fmaxf(v4,v5),fmaxf(v6,v7))),
                    fmaxf(fmaxf(fmaxf(v8,v9),fmaxf(va,vb)),
                          fmaxf(fmaxf(vc,vd),fmaxf(ve,vf))));
#pragma unroll
    for (int s = 1; s < 32; s <<= 1) m = fmaxf(m, __shfl_xor(m, s));

    float tau = m - 1.0f;
#pragma unroll 1
    for (int iter = 0; iter < 64; ++iter) {
      float s = 0.f, c = 0.f, d;
      d = v0 - tau; if (d > 0.f) { s += d; c += 1.f; }
      d = v1 - tau; if (d > 0.f) { s += d; c += 1.f; }
      d = v2 - tau; if (d > 0.f) { s += d; c += 1.f; }
      d = v3 - tau; if (d > 0.f) { s += d; c += 1.f; }
      d = v4 - tau; if (d > 0.f) { s += d; c += 1.f; }
      d = v5 - tau; if (d > 0.f) { s += d; c += 1.f; }
      d = v6 - tau; if (d > 0.f) { s += d; c += 1.f; }
      d = v7 - tau; if (d > 0.f) { s += d; c += 1.f; }
      d = v8 - tau; if (d > 0.f) { s += d; c += 1.f; }
      d = v9 - tau; if (d > 0.f) { s += d; c += 1.f; }
      d = va - tau; if (d > 0.f) { s += d; c += 1.f; }
      d = vb - tau; if (d > 0.f) { s += d; c += 1.f; }
      d = vc - tau; if (d > 0.f) { s += d; c += 1.f; }
      d = vd - tau; if (d > 0.f) { s += d; c += 1.f; }
      d = ve - tau; if (d > 0.f) { s += d; c += 1.f; }
      d = vf - tau; if (d > 0.f) { s += d; c += 1.f; }
#pragma unroll
      for (int t2 = 1; t2 < 32; t2 <<= 1) {
        s += __shfl_xor(s, t2);
        c += __shfl_xor(c, t2);
      }
      float f = s - 1.0f;
      float tnew = tau + f / c;          // c >= 1 while tau <= tau*
      bool adv = tnew > tau;             // uniform within each 32-lane half
      tau = adv ? tnew : tau;
      if (__ballot(adv) == 0ull) break;  // both rows converged
    }

    // direct global store of this lane's 16 output cols (4x float4, 64B/lane)
    float* go = z + (size_t)blockIdx.x * 8 * n + (size_t)rowInBlock * n
              + ((lane & 31) << 4);
    float4 o;
    o.x = fmaxf(v0 - tau, 0.f); o.y = fmaxf(v1 - tau, 0.f);
    o.z = fmaxf(v2 - tau, 0.f); o.w = fmaxf(v3 - tau, 0.f);
    ((float4*)go)[0] = o;
    o.x = fmaxf(v4 - tau, 0.f); o.y = fmaxf(v5 - tau, 0.f);
    o.z = fmaxf(v6 - tau, 0.f); o.w = fmaxf(v7 - tau, 0.f);
    ((float4*)go)[1] = o;
    o.x = fmaxf(v8 - tau, 0.f); o.y = fmaxf(v9 - tau, 0.f);
    o.z = fmaxf(va - tau, 0.f); o.w = fmaxf(vb - tau, 0.f);
    ((float4*)go)[2] = o;
    o.x = fmaxf(vc - tau, 0.f); o.y = fmaxf(vd - tau, 0.f);
    o.z = fmaxf(ve - tau, 0.f); o.w = fmaxf(vf - tau, 0.f);
    ((float4*)go)[3] = o;
  }
}

extern "C" void kernel_launch(void* const* d_in, const int* in_sizes, int n_in,
                              void* d_out, int out_size, void* d_ws, size_t ws_size,
                              hipStream_t stream) {
  const float* x = (const float*)d_in[0];
  float* out = (float*)d_out;
  int nrows = out_size / N_COL;  // 16384
  int nblocks = nrows / 8;       // 8 rows per 256-thread block

  fused_kernel<<<dim3(nblocks), dim3(256), 0, stream>>>(x, out);
}